// Round 1
// baseline (676.595 us; speedup 1.0000x reference)
//
#include <hip/hip_runtime.h>
#include <math.h>

#define HW 65536      // 256*256
#define CIN 64
#define EPSV 1e-5f

__global__ __launch_bounds__(256, 2) void fused_attconv_kernel(
    const float* __restrict__ kv, const float* __restrict__ q,
    const float* __restrict__ ln_g, const float* __restrict__ ln_b,
    const float* __restrict__ Wk, const float* __restrict__ bk,
    const float* __restrict__ Wv, const float* __restrict__ bv,
    const float* __restrict__ Wq, const float* __restrict__ bq,
    const float* __restrict__ scale,
    const float* __restrict__ W1, const float* __restrict__ g1, const float* __restrict__ b1,
    const float* __restrict__ W2, const float* __restrict__ g2, const float* __restrict__ b2,
    const float* __restrict__ W3, const float* __restrict__ b3,
    float* __restrict__ out)
{
    const int pix = blockIdx.x * 256 + threadIdx.x;   // grid sized exactly: 0..524287
    const int b  = pix >> 16;                          // HW == 65536
    const int hw = pix & (HW - 1);
    const float* kvp = kv + ((size_t)b << 22) + hw;    // b * 64 * 65536
    const float* qp  = q  + ((size_t)b << 22) + hw;

    // ---- issue all input loads early (coalesced, channel-strided) ----
    float xq[CIN];
    #pragma unroll
    for (int c = 0; c < CIN; ++c) xq[c] = qp[(size_t)c * HW];
    float xv[CIN];
    #pragma unroll
    for (int c = 0; c < CIN; ++c) xv[c] = kvp[(size_t)c * HW];

    // ---- qr = Wq @ q + bq  (weights wave-uniform -> scalar loads) ----
    float qr[32];
    #pragma unroll
    for (int o = 0; o < 32; ++o) {
        float a = bq[o];
        #pragma unroll
        for (int c = 0; c < CIN; ++c) a = fmaf(Wq[o * CIN + c], xq[c], a);
        qr[o] = a;
    }

    // ---- LayerNorm over channels of kv ----
    float sum = 0.f, ssq = 0.f;
    #pragma unroll
    for (int c = 0; c < CIN; ++c) { sum += xv[c]; ssq = fmaf(xv[c], xv[c], ssq); }
    const float mu  = sum * (1.0f / CIN);
    const float var = ssq * (1.0f / CIN) - mu * mu;
    const float rs  = rsqrtf(var + EPSV);
    #pragma unroll
    for (int c = 0; c < CIN; ++c)
        xv[c] = fmaf((xv[c] - mu) * rs, ln_g[c], ln_b[c]);

    // ---- k = Wk@x + bk, v = Wv@x + bv (fused: 2 indep FMA chains per o) ----
    float kk[32], vv[32];
    #pragma unroll
    for (int o = 0; o < 32; ++o) {
        float ak = bk[o], av = bv[o];
        #pragma unroll
        for (int c = 0; c < CIN; ++c) {
            ak = fmaf(Wk[o * CIN + c], xv[c], ak);
            av = fmaf(Wv[o * CIN + c], xv[c], av);
        }
        kk[o] = ak; vv[o] = av;
    }

    // ---- att = k*qr, scale, pair-softmax over (j, j+16), s = v*att ----
    float s[32];
    #pragma unroll
    for (int j = 0; j < 16; ++j) {
        const float sc = scale[j];
        const float a0 = kk[j]      * qr[j]      * sc;
        const float a1 = kk[j + 16] * qr[j + 16] * sc;
        const float e    = __expf(a1 - a0);     // inf-safe: att0->0, att1->1
        const float att0 = 1.0f / (1.0f + e);
        const float att1 = 1.0f - att0;
        s[j]      = vv[j]      * att0;
        s[j + 16] = vv[j + 16] * att1;
    }

    // ---- h1 = W1 @ s (no bias), LN16, relu ----
    float h1[16];
    #pragma unroll
    for (int o = 0; o < 16; ++o) {
        float a = 0.f;
        #pragma unroll
        for (int c = 0; c < 32; ++c) a = fmaf(W1[o * 32 + c], s[c], a);
        h1[o] = a;
    }
    {
        float s1 = 0.f, q1 = 0.f;
        #pragma unroll
        for (int o = 0; o < 16; ++o) { s1 += h1[o]; q1 = fmaf(h1[o], h1[o], q1); }
        const float m1 = s1 * (1.0f / 16.0f);
        const float v1 = q1 * (1.0f / 16.0f) - m1 * m1;
        const float r1 = rsqrtf(v1 + EPSV);
        #pragma unroll
        for (int o = 0; o < 16; ++o)
            h1[o] = fmaxf(0.f, fmaf((h1[o] - m1) * r1, g1[o], b1[o]));
    }

    // ---- h2 = W2 @ h1 (no bias), LN8, relu ----
    float h2[8];
    #pragma unroll
    for (int o = 0; o < 8; ++o) {
        float a = 0.f;
        #pragma unroll
        for (int c = 0; c < 16; ++c) a = fmaf(W2[o * 16 + c], h1[c], a);
        h2[o] = a;
    }
    {
        float s2 = 0.f, q2 = 0.f;
        #pragma unroll
        for (int o = 0; o < 8; ++o) { s2 += h2[o]; q2 = fmaf(h2[o], h2[o], q2); }
        const float m2 = s2 * (1.0f / 8.0f);
        const float v2 = q2 * (1.0f / 8.0f) - m2 * m2;
        const float r2 = rsqrtf(v2 + EPSV);
        #pragma unroll
        for (int o = 0; o < 8; ++o)
            h2[o] = fmaxf(0.f, fmaf((h2[o] - m2) * r2, g2[o], b2[o]));
    }

    // ---- out = W3 @ h2 + b3, strided coalesced store ----
    float* op = out + ((size_t)b * 16) * HW + hw;
    #pragma unroll
    for (int o = 0; o < 16; ++o) {
        float a = b3[o];
        #pragma unroll
        for (int c = 0; c < 8; ++c) a = fmaf(W3[o * 8 + c], h2[c], a);
        op[(size_t)o * HW] = a;
    }
}

extern "C" void kernel_launch(void* const* d_in, const int* in_sizes, int n_in,
                              void* d_out, int out_size, void* d_ws, size_t ws_size,
                              hipStream_t stream) {
    const float* kv    = (const float*)d_in[0];
    const float* q     = (const float*)d_in[1];
    const float* ln_g  = (const float*)d_in[2];
    const float* ln_b  = (const float*)d_in[3];
    const float* Wk    = (const float*)d_in[4];
    const float* bk    = (const float*)d_in[5];
    const float* Wv    = (const float*)d_in[6];
    const float* bv    = (const float*)d_in[7];
    const float* Wq    = (const float*)d_in[8];
    const float* bq    = (const float*)d_in[9];
    const float* scale = (const float*)d_in[10];
    const float* W1    = (const float*)d_in[11];
    const float* g1    = (const float*)d_in[12];
    const float* b1    = (const float*)d_in[13];
    const float* W2    = (const float*)d_in[14];
    const float* g2    = (const float*)d_in[15];
    const float* b2    = (const float*)d_in[16];
    const float* W3    = (const float*)d_in[17];
    const float* b3    = (const float*)d_in[18];
    float* out = (float*)d_out;

    const int total_pixels = 8 * HW;          // 524288
    const int block = 256;
    const int grid = total_pixels / block;    // 2048

    hipLaunchKernelGGL(fused_attconv_kernel, dim3(grid), dim3(block), 0, stream,
                       kv, q, ln_g, ln_b, Wk, bk, Wv, bv, Wq, bq, scale,
                       W1, g1, b1, W2, g2, b2, W3, b3, out);
}

// Round 2
// 514.674 us; speedup vs baseline: 1.3146x; 1.3146x over previous
//
#include <hip/hip_runtime.h>
#include <math.h>

#define HW 65536      // 256*256
#define CIN 64
#define EPSV 1e-5f

// ws layout (floats):
//   [0,    2048) Wk'  = Wk * ln_g (column-scaled)
//   [2048, 4096) Wv'  = Wv * ln_g
//   [4096, 4128) bk'' = bk + Wk @ ln_b
//   [4128, 4160) bv'' = bv + Wv @ ln_b
//   [4160, 4192) rsk  = rowsum(Wk')
//   [4192, 4224) rsv  = rowsum(Wv')

__global__ __launch_bounds__(256) void fold_weights_kernel(
    const float* __restrict__ Wk, const float* __restrict__ bk,
    const float* __restrict__ Wv, const float* __restrict__ bv,
    const float* __restrict__ ln_g, const float* __restrict__ ln_b,
    float* __restrict__ ws)
{
    const int t = threadIdx.x;
    for (int idx = t; idx < 2048; idx += 256) {
        const int c = idx & 63;
        const float g = ln_g[c];
        ws[idx]        = Wk[idx] * g;
        ws[2048 + idx] = Wv[idx] * g;
    }
    if (t < 32) {
        float bkp = bk[t], bvp = bv[t], rk = 0.f, rv = 0.f;
        for (int c = 0; c < 64; ++c) {
            const float wk = Wk[t * 64 + c], wv = Wv[t * 64 + c];
            const float g = ln_g[c], lb = ln_b[c];
            bkp = fmaf(wk, lb, bkp);  bvp = fmaf(wv, lb, bvp);
            rk  = fmaf(wk, g,  rk);   rv  = fmaf(wv, g,  rv);
        }
        ws[4096 + t] = bkp;
        ws[4128 + t] = bvp;
        ws[4160 + t] = rk;
        ws[4192 + t] = rv;
    }
}

__global__ __launch_bounds__(256, 4) void fused_attconv_kernel(
    const float* __restrict__ kv, const float* __restrict__ q,
    const float* __restrict__ Wq, const float* __restrict__ bq,
    const float* __restrict__ scale,
    const float* __restrict__ W1, const float* __restrict__ g1, const float* __restrict__ b1,
    const float* __restrict__ W2, const float* __restrict__ g2, const float* __restrict__ b2,
    const float* __restrict__ W3, const float* __restrict__ b3,
    const float* __restrict__ ws,
    float* __restrict__ out)
{
    const int pix = blockIdx.x * 256 + threadIdx.x;
    const int b  = pix >> 16;
    const int hw = pix & (HW - 1);
    const float* kvp = kv + ((size_t)b << 22) + hw;
    const float* qp  = q  + ((size_t)b << 22) + hw;

    const float* Wkf = ws;
    const float* Wvf = ws + 2048;
    const float* bkp = ws + 4096;
    const float* bvp = ws + 4128;
    const float* rsk = ws + 4160;
    const float* rsv = ws + 4192;

    // ================= Pass A: qr = Wq @ q + bq =================
    float qr[32];
    #pragma unroll
    for (int o = 0; o < 32; ++o) qr[o] = bq[o];

    {
        float stA[8], stB[8];
        #pragma unroll
        for (int i = 0; i < 8; ++i) stA[i] = qp[(size_t)i * HW];

        #pragma unroll 1
        for (int it = 0; it < 4; ++it) {
            const int base = it * 16;
            #pragma unroll
            for (int i = 0; i < 8; ++i) stB[i] = qp[(size_t)(base + 8 + i) * HW];
            #pragma unroll
            for (int o = 0; o < 32; ++o) {
                float a = qr[o];
                #pragma unroll
                for (int i = 0; i < 8; ++i) a = fmaf(Wq[o * 64 + base + i], stA[i], a);
                qr[o] = a;
            }
            if (it < 3) {
                #pragma unroll
                for (int i = 0; i < 8; ++i) stA[i] = qp[(size_t)(base + 16 + i) * HW];
            }
            #pragma unroll
            for (int o = 0; o < 32; ++o) {
                float a = qr[o];
                #pragma unroll
                for (int i = 0; i < 8; ++i) a = fmaf(Wq[o * 64 + base + 8 + i], stB[i], a);
                qr[o] = a;
            }
        }
    }

    // ====== Pass B: single pass over raw kv: sum, ssq, ak=Wk'@x, av=Wv'@x ======
    float ak[32], av[32];
    #pragma unroll
    for (int o = 0; o < 32; ++o) { ak[o] = 0.f; av[o] = 0.f; }
    float sum = 0.f, ssq = 0.f;

    {
        float stA[8], stB[8];
        #pragma unroll
        for (int i = 0; i < 8; ++i) stA[i] = kvp[(size_t)i * HW];

        #pragma unroll 1
        for (int it = 0; it < 4; ++it) {
            const int base = it * 16;
            #pragma unroll
            for (int i = 0; i < 8; ++i) stB[i] = kvp[(size_t)(base + 8 + i) * HW];
            #pragma unroll
            for (int i = 0; i < 8; ++i) { sum += stA[i]; ssq = fmaf(stA[i], stA[i], ssq); }
            #pragma unroll
            for (int o = 0; o < 32; ++o) {
                float a = ak[o], v = av[o];
                #pragma unroll
                for (int i = 0; i < 8; ++i) {
                    a = fmaf(Wkf[o * 64 + base + i], stA[i], a);
                    v = fmaf(Wvf[o * 64 + base + i], stA[i], v);
                }
                ak[o] = a; av[o] = v;
            }
            if (it < 3) {
                #pragma unroll
                for (int i = 0; i < 8; ++i) stA[i] = kvp[(size_t)(base + 16 + i) * HW];
            }
            #pragma unroll
            for (int i = 0; i < 8; ++i) { sum += stB[i]; ssq = fmaf(stB[i], stB[i], ssq); }
            #pragma unroll
            for (int o = 0; o < 32; ++o) {
                float a = ak[o], v = av[o];
                #pragma unroll
                for (int i = 0; i < 8; ++i) {
                    a = fmaf(Wkf[o * 64 + base + 8 + i], stB[i], a);
                    v = fmaf(Wvf[o * 64 + base + 8 + i], stB[i], v);
                }
                ak[o] = a; av[o] = v;
            }
        }
    }

    // ====== fold LN stats into k, v ======
    const float mu  = sum * (1.0f / CIN);
    const float var = ssq * (1.0f / CIN) - mu * mu;
    const float rs  = rsqrtf(var + EPSV);
    const float nrm = -rs * mu;

    float kk[32], vv[32];
    #pragma unroll
    for (int o = 0; o < 32; ++o) {
        kk[o] = fmaf(ak[o], rs, fmaf(rsk[o], nrm, bkp[o]));
        vv[o] = fmaf(av[o], rs, fmaf(rsv[o], nrm, bvp[o]));
    }

    // ====== att = k*qr, scale, pair-softmax, s = v*att (s overwrites vv) ======
    #pragma unroll
    for (int j = 0; j < 16; ++j) {
        const float sc = scale[j];
        const float a0 = kk[j]      * qr[j]      * sc;
        const float a1 = kk[j + 16] * qr[j + 16] * sc;
        const float e    = __expf(a1 - a0);
        const float att0 = 1.0f / (1.0f + e);
        const float att1 = 1.0f - att0;
        vv[j]      = vv[j]      * att0;
        vv[j + 16] = vv[j + 16] * att1;
    }

    // ====== h1 = W1 @ s, LN16, relu ======
    float h1[16];
    #pragma unroll
    for (int o = 0; o < 16; ++o) {
        float a = 0.f;
        #pragma unroll
        for (int c = 0; c < 32; ++c) a = fmaf(W1[o * 32 + c], vv[c], a);
        h1[o] = a;
    }
    {
        float s1 = 0.f, q1 = 0.f;
        #pragma unroll
        for (int o = 0; o < 16; ++o) { s1 += h1[o]; q1 = fmaf(h1[o], h1[o], q1); }
        const float m1 = s1 * (1.0f / 16.0f);
        const float v1 = q1 * (1.0f / 16.0f) - m1 * m1;
        const float r1 = rsqrtf(v1 + EPSV);
        #pragma unroll
        for (int o = 0; o < 16; ++o)
            h1[o] = fmaxf(0.f, fmaf((h1[o] - m1) * r1, g1[o], b1[o]));
    }

    // ====== h2 = W2 @ h1, LN8, relu ======
    float h2[8];
    #pragma unroll
    for (int o = 0; o < 8; ++o) {
        float a = 0.f;
        #pragma unroll
        for (int c = 0; c < 16; ++c) a = fmaf(W2[o * 16 + c], h1[c], a);
        h2[o] = a;
    }
    {
        float s2 = 0.f, q2 = 0.f;
        #pragma unroll
        for (int o = 0; o < 8; ++o) { s2 += h2[o]; q2 = fmaf(h2[o], h2[o], q2); }
        const float m2 = s2 * (1.0f / 8.0f);
        const float v2 = q2 * (1.0f / 8.0f) - m2 * m2;
        const float r2 = rsqrtf(v2 + EPSV);
        #pragma unroll
        for (int o = 0; o < 8; ++o)
            h2[o] = fmaxf(0.f, fmaf((h2[o] - m2) * r2, g2[o], b2[o]));
    }

    // ====== out = W3 @ h2 + b3 ======
    float* op = out + ((size_t)b * 16) * HW + hw;
    #pragma unroll
    for (int o = 0; o < 16; ++o) {
        float a = b3[o];
        #pragma unroll
        for (int c = 0; c < 8; ++c) a = fmaf(W3[o * 8 + c], h2[c], a);
        op[(size_t)o * HW] = a;
    }
}

extern "C" void kernel_launch(void* const* d_in, const int* in_sizes, int n_in,
                              void* d_out, int out_size, void* d_ws, size_t ws_size,
                              hipStream_t stream) {
    const float* kv    = (const float*)d_in[0];
    const float* q     = (const float*)d_in[1];
    const float* ln_g  = (const float*)d_in[2];
    const float* ln_b  = (const float*)d_in[3];
    const float* Wk    = (const float*)d_in[4];
    const float* bk    = (const float*)d_in[5];
    const float* Wv    = (const float*)d_in[6];
    const float* bv    = (const float*)d_in[7];
    const float* Wq    = (const float*)d_in[8];
    const float* bq    = (const float*)d_in[9];
    const float* scale = (const float*)d_in[10];
    const float* W1    = (const float*)d_in[11];
    const float* g1    = (const float*)d_in[12];
    const float* b1    = (const float*)d_in[13];
    const float* W2    = (const float*)d_in[14];
    const float* g2    = (const float*)d_in[15];
    const float* b2    = (const float*)d_in[16];
    const float* W3    = (const float*)d_in[17];
    const float* b3    = (const float*)d_in[18];
    float* out = (float*)d_out;
    float* ws  = (float*)d_ws;

    hipLaunchKernelGGL(fold_weights_kernel, dim3(1), dim3(256), 0, stream,
                       Wk, bk, Wv, bv, ln_g, ln_b, ws);

    const int total_pixels = 8 * HW;          // 524288
    const int block = 256;
    const int grid = total_pixels / block;    // 2048

    hipLaunchKernelGGL(fused_attconv_kernel, dim3(grid), dim3(block), 0, stream,
                       kv, q, Wq, bq, scale,
                       W1, g1, b1, W2, g2, b2, W3, b3, ws, out);
}

// Round 3
// 475.796 us; speedup vs baseline: 1.4220x; 1.0817x over previous
//
#include <hip/hip_runtime.h>
#include <math.h>

#define HW 65536      // 256*256
#define CIN 64
#define EPSV 1e-5f

// ws layout (floats):
//   [0,    2048) Wk'  = Wk * ln_g (column-scaled)
//   [2048, 4096) Wv'  = Wv * ln_g
//   [4096, 4128) bk'' = bk + Wk @ ln_b
//   [4128, 4160) bv'' = bv + Wv @ ln_b
//   [4160, 4192) rsk  = rowsum(Wk')
//   [4192, 4224) rsv  = rowsum(Wv')

__global__ __launch_bounds__(256) void fold_weights_kernel(
    const float* __restrict__ Wk, const float* __restrict__ bk,
    const float* __restrict__ Wv, const float* __restrict__ bv,
    const float* __restrict__ ln_g, const float* __restrict__ ln_b,
    float* __restrict__ ws)
{
    const int t = threadIdx.x;
    for (int idx = t; idx < 2048; idx += 256) {
        const int c = idx & 63;
        const float g = ln_g[c];
        ws[idx]        = Wk[idx] * g;
        ws[2048 + idx] = Wv[idx] * g;
    }
    if (t < 32) {
        float bkp = bk[t], bvp = bv[t], rk = 0.f, rv = 0.f;
        for (int c = 0; c < 64; ++c) {
            const float wk = Wk[t * 64 + c], wv = Wv[t * 64 + c];
            const float g = ln_g[c], lb = ln_b[c];
            bkp = fmaf(wk, lb, bkp);  bvp = fmaf(wv, lb, bvp);
            rk  = fmaf(wk, g,  rk);   rv  = fmaf(wv, g,  rv);
        }
        ws[4096 + t] = bkp;
        ws[4128 + t] = bvp;
        ws[4160 + t] = rk;
        ws[4192 + t] = rv;
    }
}

__global__ __launch_bounds__(256, 4) void fused_attconv_kernel(
    const float* __restrict__ kv, const float* __restrict__ q,
    const float* __restrict__ Wq, const float* __restrict__ bq,
    const float* __restrict__ scale,
    const float* __restrict__ W1, const float* __restrict__ g1, const float* __restrict__ b1,
    const float* __restrict__ W2, const float* __restrict__ g2, const float* __restrict__ b2,
    const float* __restrict__ W3, const float* __restrict__ b3,
    const float* __restrict__ ws,
    float* __restrict__ out)
{
    // vv offloaded to LDS: 32 ch x 256 px; each thread touches only its own
    // column -> stride-4B across lanes (2-way bank aliasing, free), no barriers.
    __shared__ float vv_s[32 * 256];

    const int tid = threadIdx.x;
    const int pix = blockIdx.x * 256 + tid;
    const int b  = pix >> 16;
    const int hw = pix & (HW - 1);
    const float* kvp = kv + ((size_t)b << 22) + hw;
    const float* qp  = q  + ((size_t)b << 22) + hw;

    const float* Wkf = ws;
    const float* Wvf = ws + 2048;
    const float* bkp = ws + 4096;
    const float* bvp = ws + 4128;
    const float* rsk = ws + 4160;
    const float* rsv = ws + 4192;

    // ====== Pass 1 (kv): sum, ssq, ak = Wk'@x, av = Wv'@x ======
    float ak[32], av[32];
    #pragma unroll
    for (int o = 0; o < 32; ++o) { ak[o] = 0.f; av[o] = 0.f; }
    float sum = 0.f, ssq = 0.f;

    {
        float stA[8], stB[8];
        #pragma unroll
        for (int i = 0; i < 8; ++i) stA[i] = kvp[(size_t)i * HW];

        #pragma unroll 1
        for (int it = 0; it < 4; ++it) {
            const int base = it * 16;
            #pragma unroll
            for (int i = 0; i < 8; ++i) stB[i] = kvp[(size_t)(base + 8 + i) * HW];
            #pragma unroll
            for (int i = 0; i < 8; ++i) { sum += stA[i]; ssq = fmaf(stA[i], stA[i], ssq); }
            #pragma unroll
            for (int o = 0; o < 32; ++o) {
                float a = ak[o], v = av[o];
                #pragma unroll
                for (int i = 0; i < 8; ++i) {
                    a = fmaf(Wkf[o * 64 + base + i], stA[i], a);
                    v = fmaf(Wvf[o * 64 + base + i], stA[i], v);
                }
                ak[o] = a; av[o] = v;
            }
            if (it < 3) {
                #pragma unroll
                for (int i = 0; i < 8; ++i) stA[i] = kvp[(size_t)(base + 16 + i) * HW];
            }
            #pragma unroll
            for (int i = 0; i < 8; ++i) { sum += stB[i]; ssq = fmaf(stB[i], stB[i], ssq); }
            #pragma unroll
            for (int o = 0; o < 32; ++o) {
                float a = ak[o], v = av[o];
                #pragma unroll
                for (int i = 0; i < 8; ++i) {
                    a = fmaf(Wkf[o * 64 + base + 8 + i], stB[i], a);
                    v = fmaf(Wvf[o * 64 + base + 8 + i], stB[i], v);
                }
                ak[o] = a; av[o] = v;
            }
        }
    }

    // ====== fold LN stats; kk stays in regs, vv -> LDS (av dies here) ======
    const float mu  = sum * (1.0f / CIN);
    const float var = ssq * (1.0f / CIN) - mu * mu;
    const float rs  = rsqrtf(var + EPSV);
    const float nrm = -rs * mu;

    float kk[32];
    #pragma unroll
    for (int o = 0; o < 32; ++o) {
        kk[o] = fmaf(ak[o], rs, fmaf(rsk[o], nrm, bkp[o]));
        vv_s[o * 256 + tid] = fmaf(av[o], rs, fmaf(rsv[o], nrm, bvp[o]));
    }

    // ====== Pass 2 (q): qr = Wq @ q + bq ======
    float qr[32];
    #pragma unroll
    for (int o = 0; o < 32; ++o) qr[o] = bq[o];

    {
        float stA[8], stB[8];
        #pragma unroll
        for (int i = 0; i < 8; ++i) stA[i] = qp[(size_t)i * HW];

        #pragma unroll 1
        for (int it = 0; it < 4; ++it) {
            const int base = it * 16;
            #pragma unroll
            for (int i = 0; i < 8; ++i) stB[i] = qp[(size_t)(base + 8 + i) * HW];
            #pragma unroll
            for (int o = 0; o < 32; ++o) {
                float a = qr[o];
                #pragma unroll
                for (int i = 0; i < 8; ++i) a = fmaf(Wq[o * 64 + base + i], stA[i], a);
                qr[o] = a;
            }
            if (it < 3) {
                #pragma unroll
                for (int i = 0; i < 8; ++i) stA[i] = qp[(size_t)(base + 16 + i) * HW];
            }
            #pragma unroll
            for (int o = 0; o < 32; ++o) {
                float a = qr[o];
                #pragma unroll
                for (int i = 0; i < 8; ++i) a = fmaf(Wq[o * 64 + base + 8 + i], stB[i], a);
                qr[o] = a;
            }
        }
    }

    // ====== att = k*qr, scale, pair-softmax, s = v*att (vv from LDS) ======
    float s[32];
    #pragma unroll
    for (int j = 0; j < 16; ++j) {
        const float sc = scale[j];
        const float a0 = kk[j]      * qr[j]      * sc;
        const float a1 = kk[j + 16] * qr[j + 16] * sc;
        const float e    = __expf(a1 - a0);
        const float att0 = 1.0f / (1.0f + e);
        const float att1 = 1.0f - att0;
        s[j]      = vv_s[j * 256 + tid]        * att0;
        s[j + 16] = vv_s[(j + 16) * 256 + tid] * att1;
    }

    // ====== h1 = W1 @ s, LN16, relu ======
    float h1[16];
    #pragma unroll
    for (int o = 0; o < 16; ++o) {
        float a = 0.f;
        #pragma unroll
        for (int c = 0; c < 32; ++c) a = fmaf(W1[o * 32 + c], s[c], a);
        h1[o] = a;
    }
    {
        float s1 = 0.f, q1 = 0.f;
        #pragma unroll
        for (int o = 0; o < 16; ++o) { s1 += h1[o]; q1 = fmaf(h1[o], h1[o], q1); }
        const float m1 = s1 * (1.0f / 16.0f);
        const float v1 = q1 * (1.0f / 16.0f) - m1 * m1;
        const float r1 = rsqrtf(v1 + EPSV);
        #pragma unroll
        for (int o = 0; o < 16; ++o)
            h1[o] = fmaxf(0.f, fmaf((h1[o] - m1) * r1, g1[o], b1[o]));
    }

    // ====== h2 = W2 @ h1, LN8, relu ======
    float h2[8];
    #pragma unroll
    for (int o = 0; o < 8; ++o) {
        float a = 0.f;
        #pragma unroll
        for (int c = 0; c < 16; ++c) a = fmaf(W2[o * 16 + c], h1[c], a);
        h2[o] = a;
    }
    {
        float s2 = 0.f, q2 = 0.f;
        #pragma unroll
        for (int o = 0; o < 8; ++o) { s2 += h2[o]; q2 = fmaf(h2[o], h2[o], q2); }
        const float m2 = s2 * (1.0f / 8.0f);
        const float v2 = q2 * (1.0f / 8.0f) - m2 * m2;
        const float r2 = rsqrtf(v2 + EPSV);
        #pragma unroll
        for (int o = 0; o < 8; ++o)
            h2[o] = fmaxf(0.f, fmaf((h2[o] - m2) * r2, g2[o], b2[o]));
    }

    // ====== out = W3 @ h2 + b3 ======
    float* op = out + ((size_t)b * 16) * HW + hw;
    #pragma unroll
    for (int o = 0; o < 16; ++o) {
        float a = b3[o];
        #pragma unroll
        for (int c = 0; c < 8; ++c) a = fmaf(W3[o * 8 + c], h2[c], a);
        op[(size_t)o * HW] = a;
    }
}

extern "C" void kernel_launch(void* const* d_in, const int* in_sizes, int n_in,
                              void* d_out, int out_size, void* d_ws, size_t ws_size,
                              hipStream_t stream) {
    const float* kv    = (const float*)d_in[0];
    const float* q     = (const float*)d_in[1];
    const float* ln_g  = (const float*)d_in[2];
    const float* ln_b  = (const float*)d_in[3];
    const float* Wk    = (const float*)d_in[4];
    const float* bk    = (const float*)d_in[5];
    const float* Wv    = (const float*)d_in[6];
    const float* bv    = (const float*)d_in[7];
    const float* Wq    = (const float*)d_in[8];
    const float* bq    = (const float*)d_in[9];
    const float* scale = (const float*)d_in[10];
    const float* W1    = (const float*)d_in[11];
    const float* g1    = (const float*)d_in[12];
    const float* b1    = (const float*)d_in[13];
    const float* W2    = (const float*)d_in[14];
    const float* g2    = (const float*)d_in[15];
    const float* b2    = (const float*)d_in[16];
    const float* W3    = (const float*)d_in[17];
    const float* b3    = (const float*)d_in[18];
    float* out = (float*)d_out;
    float* ws  = (float*)d_ws;

    hipLaunchKernelGGL(fold_weights_kernel, dim3(1), dim3(256), 0, stream,
                       Wk, bk, Wv, bv, ln_g, ln_b, ws);

    const int total_pixels = 8 * HW;          // 524288
    const int block = 256;
    const int grid = total_pixels / block;    // 2048

    hipLaunchKernelGGL(fused_attconv_kernel, dim3(grid), dim3(block), 0, stream,
                       kv, q, Wq, bq, scale,
                       W1, g1, b1, W2, g2, b2, W3, b3, ws, out);
}

// Round 4
// 429.406 us; speedup vs baseline: 1.5757x; 1.1080x over previous
//
#include <hip/hip_runtime.h>
#include <math.h>

#define HW 65536      // 256*256
#define CIN 64
#define EPSV 1e-5f

// Constant-address-space cast (composable_kernel pattern): uniform loads from
// AS(4) pointers compile to s_load -> weights live in SGPRs, FMA = v_fmac v,s,v.
#define CSPACE(p) ((const __attribute__((address_space(4))) float*)(p))

// ws layout (floats):
//   [0,    2048) Wk'  = Wk * ln_g (column-scaled)
//   [2048, 4096) Wv'  = Wv * ln_g
//   [4096, 4128) bk'' = bk + Wk @ ln_b
//   [4128, 4160) bv'' = bv + Wv @ ln_b
//   [4160, 4192) rsk  = rowsum(Wk')
//   [4192, 4224) rsv  = rowsum(Wv')

__global__ __launch_bounds__(256) void fold_weights_kernel(
    const float* __restrict__ Wk, const float* __restrict__ bk,
    const float* __restrict__ Wv, const float* __restrict__ bv,
    const float* __restrict__ ln_g, const float* __restrict__ ln_b,
    float* __restrict__ ws)
{
    const int t = threadIdx.x;
    for (int idx = t; idx < 2048; idx += 256) {
        const int c = idx & 63;
        const float g = ln_g[c];
        ws[idx]        = Wk[idx] * g;
        ws[2048 + idx] = Wv[idx] * g;
    }
    if (t < 32) {
        float bkp = bk[t], bvp = bv[t], rk = 0.f, rv = 0.f;
        for (int c = 0; c < 64; ++c) {
            const float wk = Wk[t * 64 + c], wv = Wv[t * 64 + c];
            const float g = ln_g[c], lb = ln_b[c];
            bkp = fmaf(wk, lb, bkp);  bvp = fmaf(wv, lb, bvp);
            rk  = fmaf(wk, g,  rk);   rv  = fmaf(wv, g,  rv);
        }
        ws[4096 + t] = bkp;
        ws[4128 + t] = bvp;
        ws[4160 + t] = rk;
        ws[4192 + t] = rv;
    }
}

__global__ __launch_bounds__(256, 4) void fused_attconv_kernel(
    const float* __restrict__ kv, const float* __restrict__ q,
    const float* __restrict__ Wq_, const float* __restrict__ bq_,
    const float* __restrict__ scale_,
    const float* __restrict__ W1_, const float* __restrict__ g1_, const float* __restrict__ b1_,
    const float* __restrict__ W2_, const float* __restrict__ g2_, const float* __restrict__ b2_,
    const float* __restrict__ W3_, const float* __restrict__ b3_,
    const float* __restrict__ ws_,
    float* __restrict__ out)
{
    // All wave-uniform-read arrays through the constant (scalar) path:
    const auto Wq    = CSPACE(Wq_);
    const auto bq    = CSPACE(bq_);
    const auto scale = CSPACE(scale_);
    const auto W1    = CSPACE(W1_);
    const auto g1    = CSPACE(g1_);
    const auto b1    = CSPACE(b1_);
    const auto W2    = CSPACE(W2_);
    const auto g2    = CSPACE(g2_);
    const auto b2    = CSPACE(b2_);
    const auto W3    = CSPACE(W3_);
    const auto b3    = CSPACE(b3_);
    const auto Wkf   = CSPACE(ws_);
    const auto Wvf   = CSPACE(ws_ + 2048);
    const auto bkp   = CSPACE(ws_ + 4096);
    const auto bvp   = CSPACE(ws_ + 4128);
    const auto rsk   = CSPACE(ws_ + 4160);
    const auto rsv   = CSPACE(ws_ + 4192);

    // vv offloaded to LDS: 32 ch x 256 px; each thread touches only its own
    // column -> 2-way bank aliasing (free), no barriers needed.
    __shared__ float vv_s[32 * 256];

    const int tid = threadIdx.x;
    const int pix = blockIdx.x * 256 + tid;
    const int b  = pix >> 16;
    const int hw = pix & (HW - 1);
    const float* kvp = kv + ((size_t)b << 22) + hw;
    const float* qp  = q  + ((size_t)b << 22) + hw;

    // ====== Pass 1 (kv): sum, ssq, ak = Wk'@x, av = Wv'@x ======
    float ak[32], av[32];
    #pragma unroll
    for (int o = 0; o < 32; ++o) { ak[o] = 0.f; av[o] = 0.f; }
    float sum = 0.f, ssq = 0.f;

    {
        float stA[8], stB[8];
        #pragma unroll
        for (int i = 0; i < 8; ++i) stA[i] = kvp[(size_t)i * HW];

        #pragma unroll 1
        for (int it = 0; it < 4; ++it) {
            const int base = it * 16;
            #pragma unroll
            for (int i = 0; i < 8; ++i) stB[i] = kvp[(size_t)(base + 8 + i) * HW];
            #pragma unroll
            for (int i = 0; i < 8; ++i) { sum += stA[i]; ssq = fmaf(stA[i], stA[i], ssq); }
            #pragma unroll
            for (int o = 0; o < 32; ++o) {
                float a = ak[o], v = av[o];
                #pragma unroll
                for (int i = 0; i < 8; ++i) {
                    a = fmaf(Wkf[o * 64 + base + i], stA[i], a);
                    v = fmaf(Wvf[o * 64 + base + i], stA[i], v);
                }
                ak[o] = a; av[o] = v;
            }
            if (it < 3) {
                #pragma unroll
                for (int i = 0; i < 8; ++i) stA[i] = kvp[(size_t)(base + 16 + i) * HW];
            }
            #pragma unroll
            for (int i = 0; i < 8; ++i) { sum += stB[i]; ssq = fmaf(stB[i], stB[i], ssq); }
            #pragma unroll
            for (int o = 0; o < 32; ++o) {
                float a = ak[o], v = av[o];
                #pragma unroll
                for (int i = 0; i < 8; ++i) {
                    a = fmaf(Wkf[o * 64 + base + 8 + i], stB[i], a);
                    v = fmaf(Wvf[o * 64 + base + 8 + i], stB[i], v);
                }
                ak[o] = a; av[o] = v;
            }
        }
    }

    // ====== fold LN stats; kk stays in regs, vv -> LDS (av dies here) ======
    const float mu  = sum * (1.0f / CIN);
    const float var = ssq * (1.0f / CIN) - mu * mu;
    const float rs  = rsqrtf(var + EPSV);
    const float nrm = -rs * mu;

    float kk[32];
    #pragma unroll
    for (int o = 0; o < 32; ++o) {
        kk[o] = fmaf(ak[o], rs, fmaf(rsk[o], nrm, bkp[o]));
        vv_s[o * 256 + tid] = fmaf(av[o], rs, fmaf(rsv[o], nrm, bvp[o]));
    }

    // ====== Pass 2 (q): qr = Wq @ q + bq ======
    float qr[32];
    #pragma unroll
    for (int o = 0; o < 32; ++o) qr[o] = bq[o];

    {
        float stA[8], stB[8];
        #pragma unroll
        for (int i = 0; i < 8; ++i) stA[i] = qp[(size_t)i * HW];

        #pragma unroll 1
        for (int it = 0; it < 4; ++it) {
            const int base = it * 16;
            #pragma unroll
            for (int i = 0; i < 8; ++i) stB[i] = qp[(size_t)(base + 8 + i) * HW];
            #pragma unroll
            for (int o = 0; o < 32; ++o) {
                float a = qr[o];
                #pragma unroll
                for (int i = 0; i < 8; ++i) a = fmaf(Wq[o * 64 + base + i], stA[i], a);
                qr[o] = a;
            }
            if (it < 3) {
                #pragma unroll
                for (int i = 0; i < 8; ++i) stA[i] = qp[(size_t)(base + 16 + i) * HW];
            }
            #pragma unroll
            for (int o = 0; o < 32; ++o) {
                float a = qr[o];
                #pragma unroll
                for (int i = 0; i < 8; ++i) a = fmaf(Wq[o * 64 + base + 8 + i], stB[i], a);
                qr[o] = a;
            }
        }
    }

    // ====== att = k*qr, scale, pair-softmax, s = v*att (vv from LDS) ======
    float s[32];
    #pragma unroll
    for (int j = 0; j < 16; ++j) {
        const float sc = scale[j];
        const float a0 = kk[j]      * qr[j]      * sc;
        const float a1 = kk[j + 16] * qr[j + 16] * sc;
        const float e    = __expf(a1 - a0);
        const float att0 = 1.0f / (1.0f + e);
        const float att1 = 1.0f - att0;
        s[j]      = vv_s[j * 256 + tid]        * att0;
        s[j + 16] = vv_s[(j + 16) * 256 + tid] * att1;
    }

    // ====== h1 = W1 @ s, LN16, relu ======
    float h1[16];
    #pragma unroll
    for (int o = 0; o < 16; ++o) {
        float a = 0.f;
        #pragma unroll
        for (int c = 0; c < 32; ++c) a = fmaf(W1[o * 32 + c], s[c], a);
        h1[o] = a;
    }
    {
        float s1 = 0.f, q1 = 0.f;
        #pragma unroll
        for (int o = 0; o < 16; ++o) { s1 += h1[o]; q1 = fmaf(h1[o], h1[o], q1); }
        const float m1 = s1 * (1.0f / 16.0f);
        const float v1 = q1 * (1.0f / 16.0f) - m1 * m1;
        const float r1 = rsqrtf(v1 + EPSV);
        #pragma unroll
        for (int o = 0; o < 16; ++o)
            h1[o] = fmaxf(0.f, fmaf((h1[o] - m1) * r1, g1[o], b1[o]));
    }

    // ====== h2 = W2 @ h1, LN8, relu ======
    float h2[8];
    #pragma unroll
    for (int o = 0; o < 8; ++o) {
        float a = 0.f;
        #pragma unroll
        for (int c = 0; c < 16; ++c) a = fmaf(W2[o * 16 + c], h1[c], a);
        h2[o] = a;
    }
    {
        float s2 = 0.f, q2 = 0.f;
        #pragma unroll
        for (int o = 0; o < 8; ++o) { s2 += h2[o]; q2 = fmaf(h2[o], h2[o], q2); }
        const float m2 = s2 * (1.0f / 8.0f);
        const float v2 = q2 * (1.0f / 8.0f) - m2 * m2;
        const float r2 = rsqrtf(v2 + EPSV);
        #pragma unroll
        for (int o = 0; o < 8; ++o)
            h2[o] = fmaxf(0.f, fmaf((h2[o] - m2) * r2, g2[o], b2[o]));
    }

    // ====== out = W3 @ h2 + b3 ======
    float* op = out + ((size_t)b * 16) * HW + hw;
    #pragma unroll
    for (int o = 0; o < 16; ++o) {
        float a = b3[o];
        #pragma unroll
        for (int c = 0; c < 8; ++c) a = fmaf(W3[o * 8 + c], h2[c], a);
        op[(size_t)o * HW] = a;
    }
}

extern "C" void kernel_launch(void* const* d_in, const int* in_sizes, int n_in,
                              void* d_out, int out_size, void* d_ws, size_t ws_size,
                              hipStream_t stream) {
    const float* kv    = (const float*)d_in[0];
    const float* q     = (const float*)d_in[1];
    const float* ln_g  = (const float*)d_in[2];
    const float* ln_b  = (const float*)d_in[3];
    const float* Wk    = (const float*)d_in[4];
    const float* bk    = (const float*)d_in[5];
    const float* Wv    = (const float*)d_in[6];
    const float* bv    = (const float*)d_in[7];
    const float* Wq    = (const float*)d_in[8];
    const float* bq    = (const float*)d_in[9];
    const float* scale = (const float*)d_in[10];
    const float* W1    = (const float*)d_in[11];
    const float* g1    = (const float*)d_in[12];
    const float* b1    = (const float*)d_in[13];
    const float* W2    = (const float*)d_in[14];
    const float* g2    = (const float*)d_in[15];
    const float* b2    = (const float*)d_in[16];
    const float* W3    = (const float*)d_in[17];
    const float* b3    = (const float*)d_in[18];
    float* out = (float*)d_out;
    float* ws  = (float*)d_ws;

    hipLaunchKernelGGL(fold_weights_kernel, dim3(1), dim3(256), 0, stream,
                       Wk, bk, Wv, bv, ln_g, ln_b, ws);

    const int total_pixels = 8 * HW;          // 524288
    const int block = 256;
    const int grid = total_pixels / block;    // 2048

    hipLaunchKernelGGL(fused_attconv_kernel, dim3(grid), dim3(block), 0, stream,
                       kv, q, Wq, bq, scale,
                       W1, g1, b1, W2, g2, b2, W3, b3, ws, out);
}